// Round 4
// baseline (104.554 us; speedup 1.0000x reference)
//
#include <hip/hip_runtime.h>

// Problem constants
#define NB   8192
#define ND   256
#define NH1  50
#define NH2  32
#define NH3  18
#define RPB  16              // rows per block
#define TPB  256             // threads per block (4 waves)
#define NBLK (NB / RPB)      // 512 blocks
#define WSS  40              // per-block ws slot stride (floats)

// ws layout: ws[b*WSS + c], c: [0..17] ysum part, [18..35] colsum(W_user) part,
//            [36] sum(log_denom) part. No atomics, no zero-init needed.

__device__ __forceinline__ float sigmoidf_fast(float v) {
    return 1.0f / (1.0f + __expf(-v));
}

// DPP-based 16-lane-group sum: VALU pipe only (no LDS/ds_bpermute).
template <int CTRL>
__device__ __forceinline__ float dpp_addf(float v) {
    return v + __int_as_float(__builtin_amdgcn_update_dpp(
        0, __float_as_int(v), CTRL, 0xF, 0xF, true));
}
__device__ __forceinline__ float sum16(float v) {
    v = dpp_addf<0xB1>(v);    // quad_perm xor 1
    v = dpp_addf<0x4E>(v);    // quad_perm xor 2
    v = dpp_addf<0x124>(v);   // row_ror:4
    v = dpp_addf<0x128>(v);   // row_ror:8
    return v;
}

// async global->LDS, 16B per lane, wave-uniform LDS base + lane*16
__device__ __forceinline__ void gload_lds16(const float* g, float* l) {
    __builtin_amdgcn_global_load_lds(
        (const __attribute__((address_space(1))) unsigned int*)g,
        (__attribute__((address_space(3))) unsigned int*)l, 16, 0, 0);
}

// Operand flip vs R1: W1 lives in REGISTERS (reused across all 16 rows),
// x streams from LDS (broadcast across jsl groups, <=2-way conflicts).
// Thread (ksl = t&15, jsl = t>>4): k in {64q+4*ksl+i}, j in {jsl+16s}.
__global__ __launch_bounds__(TPB) void fused_main(
    const float* __restrict__ x, const float* __restrict__ y,
    const float* __restrict__ W1, const float* __restrict__ b1,
    const float* __restrict__ W2, const float* __restrict__ b2,
    const float* __restrict__ W3, const float* __restrict__ b3,
    float* __restrict__ out, float* __restrict__ ws)
{
    __shared__ alignas(16) float xl[RPB * ND];      // 16384 B, x tile [16][256]
    __shared__ alignas(16) float h1l[RPB][52];      // 3328 B (stride 52)
    __shared__ alignas(16) float w2l[NH1 * NH2];    // 6400 B
    __shared__ alignas(16) float w3l[NH2 * NH3];    // 2304 B
    __shared__ alignas(16) float h2l[RPB][NH2 + 2]; // stride 34
    __shared__ alignas(16) float wul[RPB][NH3 + 1]; // stride 19
    // total ~31.8 KB -> 2 blocks/CU resident (8 waves/CU)

    const int t    = threadIdx.x;
    const int ksl  = t & 15;          // k-slice id (16-lane DPP group)
    const int jsl  = t >> 4;          // j-slice id; doubles as row for L2/L3
    const int lane = t & 63;
    const int wave = t >> 6;          // 0..3

    // ---- stage x tile (16 rows x 1 KB) via global_load_lds, linear ----
    const float* xblk = x + (size_t)blockIdx.x * RPB * ND;
#pragma unroll
    for (int i = 0; i < 4; ++i) {
        const int r = wave + 4 * i;               // wave-uniform row id
        gload_lds16(xblk + r * ND + lane * 4, xl + r * ND);
    }

    // ---- W1 -> registers (one-time; W1 is 50 KB, L2-resident) ----
    // s = 0..2 always valid (j = jsl+16s <= 47); s = 3 valid only for jsl < 2.
    float w1r[4][4][4];               // [q][i][s]
    float b1r[4];
#pragma unroll
    for (int s = 0; s < 3; ++s) b1r[s] = b1[jsl + 16 * s];
    b1r[3] = (jsl < 2) ? b1[jsl + 48] : 0.0f;
#pragma unroll
    for (int q = 0; q < 4; ++q) {
#pragma unroll
        for (int i = 0; i < 4; ++i) {
            const int k = 64 * q + 4 * ksl + i;
            const float* wk = W1 + k * NH1;
#pragma unroll
            for (int s = 0; s < 3; ++s) w1r[q][i][s] = wk[jsl + 16 * s];
            w1r[q][i][3] = (jsl < 2) ? wk[jsl + 48] : 0.0f;
        }
    }

    for (int e = t; e < NH1 * NH2; e += TPB) w2l[e] = W2[e];
    for (int e = t; e < NH2 * NH3; e += TPB) w3l[e] = W3[e];
    __syncthreads();

    // ---- layer 1: per row, read x k-slice (4 x b128), 64 FMA, DPP-reduce ----
#pragma unroll 4
    for (int r = 0; r < RPB; ++r) {
        float4 xq[4];
#pragma unroll
        for (int q = 0; q < 4; ++q)
            xq[q] = *reinterpret_cast<const float4*>(&xl[r * ND + 64 * q + 4 * ksl]);
        float acc[4] = {0.0f, 0.0f, 0.0f, 0.0f};
#pragma unroll
        for (int q = 0; q < 4; ++q) {
            const float xe[4] = {xq[q].x, xq[q].y, xq[q].z, xq[q].w};
#pragma unroll
            for (int i = 0; i < 4; ++i) {
#pragma unroll
                for (int s = 0; s < 4; ++s)
                    acc[s] = fmaf(xe[i], w1r[q][i][s], acc[s]);
            }
        }
#pragma unroll
        for (int s = 0; s < 4; ++s) acc[s] = sum16(acc[s]);
        // only one ksl-lane finalizes/stores (sigmoid computed 16x less)
        if (ksl == r) {
#pragma unroll
            for (int s = 0; s < 3; ++s)
                h1l[r][jsl + 16 * s] = sigmoidf_fast(acc[s] + b1r[s]);
            if (jsl < 2)
                h1l[r][jsl + 48] = sigmoidf_fast(acc[3] + b1r[3]);
        }
    }
    __syncthreads();   // h1l written by scattered lanes across waves

    // ---- layer 2: row = jsl, lane computes cols {2*ksl, 2*ksl+1} ----
    const int row  = jsl;
    const int grow = blockIdx.x * RPB + row;
    {
        const float2 bb = *reinterpret_cast<const float2*>(b2 + 2 * ksl);
        float h2a = bb.x, h2b = bb.y;
#pragma unroll
        for (int jj = 0; jj < 25; ++jj) {
            const float2 hh = *reinterpret_cast<const float2*>(&h1l[row][2 * jj]);
            const float2 wA = *reinterpret_cast<const float2*>(&w2l[(2 * jj)     * NH2 + 2 * ksl]);
            const float2 wB = *reinterpret_cast<const float2*>(&w2l[(2 * jj + 1) * NH2 + 2 * ksl]);
            h2a = fmaf(hh.x, wA.x, fmaf(hh.y, wB.x, h2a));
            h2b = fmaf(hh.x, wA.y, fmaf(hh.y, wB.y, h2b));
        }
        *reinterpret_cast<float2*>(&h2l[row][2 * ksl]) =
            make_float2(sigmoidf_fast(h2a), sigmoidf_fast(h2b));
    }
    // NO barrier: layer 3 reads h2l[row][*] written by this same 16-lane group
    // (consecutive lanes 16*jsl..16*jsl+15, same wave; lgkmcnt orders).

    // ---- layer 3: lane computes col ksl (and 16+ksl for ksl<2) ----
    {
        float a0 = b3[ksl];
        float a1 = (ksl < 2) ? b3[16 + ksl] : 0.0f;
#pragma unroll
        for (int j = 0; j < NH2; ++j) {
            const float h = h2l[row][j];              // broadcast within 16-group
            a0 = fmaf(h, w3l[j * NH3 + ksl], a0);
            if (ksl < 2) a1 = fmaf(h, w3l[j * NH3 + 16 + ksl], a1);
        }
        wul[row][ksl] = a0;
        out[(size_t)grow * NH3 + ksl] = a0;
        if (ksl < 2) {
            wul[row][16 + ksl] = a1;
            out[(size_t)grow * NH3 + 16 + ksl] = a1;
        }
    }
    __syncthreads();   // epilogue wave reads all 16 rows (cross-wave)

    // ---- epilogue on wave 0: factorized LSE + block reductions ----
    if (t < 64) {
        const bool act = t < RPB;
        float wv[NH3], yv[NH3];
        float ld = 0.0f;
        if (act) {
            const float* yrow = y + (size_t)(blockIdx.x * RPB + t) * NH3;
#pragma unroll
            for (int c = 0; c < NH3; ++c) {
                wv[c] = wul[t][c];
                yv[c] = yrow[c];
            }
            // factorized logsumexp over cartesian one-hot cases:
            // groups [0,2) [2,6) [6,10) [10,18)
            float m = fmaxf(wv[0], wv[1]);
            ld += m + __logf(__expf(wv[0] - m) + __expf(wv[1] - m));
            m = fmaxf(fmaxf(wv[2], wv[3]), fmaxf(wv[4], wv[5]));
            ld += m + __logf(__expf(wv[2] - m) + __expf(wv[3] - m) +
                             __expf(wv[4] - m) + __expf(wv[5] - m));
            m = fmaxf(fmaxf(wv[6], wv[7]), fmaxf(wv[8], wv[9]));
            ld += m + __logf(__expf(wv[6] - m) + __expf(wv[7] - m) +
                             __expf(wv[8] - m) + __expf(wv[9] - m));
            m = wv[10];
#pragma unroll
            for (int i = 11; i < NH3; ++i) m = fmaxf(m, wv[i]);
            float s = 0.0f;
#pragma unroll
            for (int i = 10; i < NH3; ++i) s += __expf(wv[i] - m);
            ld += m + __logf(s);
        } else {
#pragma unroll
            for (int c = 0; c < NH3; ++c) { wv[c] = 0.0f; yv[c] = 0.0f; }
        }

        // 16-lane DPP reductions; lanes 0..15 hold block totals
        ld = sum16(ld);
#pragma unroll
        for (int c = 0; c < NH3; ++c) {
            wv[c] = sum16(wv[c]);
            yv[c] = sum16(yv[c]);
        }
        if (t == 0) {
            float* slot = ws + (size_t)blockIdx.x * WSS;
#pragma unroll
            for (int c = 0; c < NH3; ++c) {
                slot[c]       = yv[c];       // ysum partial
                slot[NH3 + c] = wv[c];       // colsum(W_user) partial
            }
            slot[36] = ld;                   // log_denom partial
        }
    }
}

__global__ __launch_bounds__(256) void finalize_loss(
    const float* __restrict__ ws, float* __restrict__ out)
{
    __shared__ double part[4][37];
    const int t = threadIdx.x;
    const int w = t >> 6, l = t & 63;
    if (l < 37) {
        // 4 independent accumulators: breaks the serial add chain so the
        // 128 global loads pipeline instead of serializing on latency.
        double a0 = 0.0, a1 = 0.0, a2 = 0.0, a3 = 0.0;
        const int base = w * (NBLK / 4);
        for (int b = 0; b < NBLK / 4; b += 4) {
            a0 += (double)ws[(size_t)(base + b    ) * WSS + l];
            a1 += (double)ws[(size_t)(base + b + 1) * WSS + l];
            a2 += (double)ws[(size_t)(base + b + 2) * WSS + l];
            a3 += (double)ws[(size_t)(base + b + 3) * WSS + l];
        }
        part[w][l] = (a0 + a1) + (a2 + a3);
    }
    __syncthreads();
    if (t == 0) {
        double tot[37];
#pragma unroll
        for (int c = 0; c < 37; ++c)
            tot[c] = part[0][c] + part[1][c] + part[2][c] + part[3][c];
        double s = 0.0;
#pragma unroll
        for (int c = 0; c < NH3; ++c)
            s += tot[NH3 + c] * tot[c];             // colsum(W_user) . ysum == sum(S)
        out[(size_t)NB * NH3] = (float)(-(s - tot[36]));
    }
}

extern "C" void kernel_launch(void* const* d_in, const int* in_sizes, int n_in,
                              void* d_out, int out_size, void* d_ws, size_t ws_size,
                              hipStream_t stream) {
    const float* x  = (const float*)d_in[0];
    const float* y  = (const float*)d_in[1];
    const float* W1 = (const float*)d_in[2];
    const float* b1 = (const float*)d_in[3];
    const float* W2 = (const float*)d_in[4];
    const float* b2 = (const float*)d_in[5];
    const float* W3 = (const float*)d_in[6];
    const float* b3 = (const float*)d_in[7];
    // d_in[8] (cases) folded into the factorized logsumexp.
    float* out = (float*)d_out;
    float* ws  = (float*)d_ws;

    fused_main<<<dim3(NBLK), dim3(TPB), 0, stream>>>(x, y, W1, b1, W2, b2, W3, b3, out, ws);
    finalize_loss<<<dim3(1), dim3(256), 0, stream>>>(ws, out);
}

// Round 5
// 94.276 us; speedup vs baseline: 1.1090x; 1.1090x over previous
//
#include <hip/hip_runtime.h>

// Problem constants
#define NB   8192
#define ND   256
#define NH1  50
#define NH2  32
#define NH3  18
#define RPB  16              // rows per block
#define TPB  256             // threads per block (4 waves)
#define NBLK (NB / RPB)      // 512 blocks
#define WSS  40              // per-block ws slot stride (floats)

// ws layout: ws[b*WSS + c], c: [0..17] ysum part, [18..35] colsum(W_user) part,
//            [36] sum(log_denom) part. No atomics, no zero-init needed.

__device__ __forceinline__ float sigmoidf_fast(float v) {
    return 1.0f / (1.0f + __expf(-v));
}

// DPP-based 16-lane-group sum: VALU pipe only (no LDS/ds_bpermute).
template <int CTRL>
__device__ __forceinline__ float dpp_addf(float v) {
    return v + __int_as_float(__builtin_amdgcn_update_dpp(
        0, __float_as_int(v), CTRL, 0xF, 0xF, true));
}
__device__ __forceinline__ float sum16(float v) {
    v = dpp_addf<0xB1>(v);    // quad_perm xor 1
    v = dpp_addf<0x4E>(v);    // quad_perm xor 2
    v = dpp_addf<0x124>(v);   // row_ror:4
    v = dpp_addf<0x128>(v);   // row_ror:8
    return v;
}

// async global->LDS, 16B per lane, wave-uniform LDS base + lane*16
__device__ __forceinline__ void gload_lds16(const float* g, float* l) {
    __builtin_amdgcn_global_load_lds(
        (const __attribute__((address_space(1))) unsigned int*)g,
        (__attribute__((address_space(3))) unsigned int*)l, 16, 0, 0);
}

// R1 shell (proven 94.7): W1 in LDS (broadcast), x in registers, 8 waves/CU.
// Only change: layer-1 reads the contiguous row-pair (kA,kA+1) = 100 aligned
// floats as 25 ds_read_b128 instead of 50 ds_read_b64 (half the LDS instrs).
__global__ __launch_bounds__(TPB) void fused_main(
    const float* __restrict__ x, const float* __restrict__ y,
    const float* __restrict__ W1, const float* __restrict__ b1,
    const float* __restrict__ W2, const float* __restrict__ b2,
    const float* __restrict__ W3, const float* __restrict__ b3,
    float* __restrict__ out, float* __restrict__ ws)
{
    __shared__ alignas(16) float w1l[ND * NH1];     // 51200 B, row-major [k][j]
    __shared__ alignas(16) float w2l[NH1 * NH2];    // 6400 B
    __shared__ alignas(16) float w3l[NH2 * NH3];    // 2304 B
    __shared__ alignas(16) float h2l[RPB][NH2 + 2]; // stride 34
    __shared__ alignas(16) float wul[RPB][NH3 + 1]; // stride 19
    // total 63296 B -> 2 blocks/CU (8 waves/CU)

    const int t    = threadIdx.x;
    const int row  = t >> 4;          // 0..15 local row
    const int ksl  = t & 15;          // k-slice within row
    const int lane = t & 63;
    const int wave = t >> 6;          // 0..3
    const int grow = blockIdx.x * RPB + row;

    // ---- issue x loads first (registers; stay in flight over staging) ----
    // lane's k-set: {32c + 2ksl, 32c + 2ksl + 1}, c = 0..7  (coalesced float2)
    const float* xrow = x + (size_t)grow * ND + 2 * ksl;
    float2 xv[8];
#pragma unroll
    for (int c = 0; c < 8; ++c)
        xv[c] = *reinterpret_cast<const float2*>(xrow + 32 * c);

    // ---- stage W1 row-major via global_load_lds: 50 chunks of 1024 B ----
#pragma unroll
    for (int i = 0; i < 13; ++i) {
        const int c = wave + 4 * i;               // wave-uniform chunk id
        if (c < 50)
            gload_lds16(W1 + c * 256 + lane * 4, w1l + c * 256);
    }
    for (int e = t; e < NH1 * NH2; e += TPB) w2l[e] = W2[e];
    for (int e = t; e < NH2 * NH3; e += TPB) w3l[e] = W3[e];
    __syncthreads();

    // ---- layer 1: rows kA=32c+2ksl, kA+1 are 100 CONTIGUOUS 16B-aligned
    //      floats in w1l -> pure ds_read_b128 (bank = 4*ksl mod 32: 2-way,
    //      free); 4 row-groups per wave read identical addrs -> broadcast ----
    float h1[NH1];
#pragma unroll
    for (int j = 0; j < NH1; ++j) h1[j] = 0.0f;
#pragma unroll
    for (int c = 0; c < 8; ++c) {
        const int kA = 32 * c + 2 * ksl;
        const float* wp = &w1l[kA * NH1];
        const float xa = xv[c].x, xb = xv[c].y;   // x[kA], x[kA+1]
#pragma unroll
        for (int q = 0; q < 25; ++q) {
            const float4 w = *reinterpret_cast<const float4*>(wp + 4 * q);
            const float we[4] = {w.x, w.y, w.z, w.w};
#pragma unroll
            for (int s = 0; s < 4; ++s) {
                const int e = 4 * q + s;          // compile-time after unroll
                if (e < NH1) h1[e]       = fmaf(xa, we[s], h1[e]);
                else         h1[e - NH1] = fmaf(xb, we[s], h1[e - NH1]);
            }
        }
    }
    // 16-lane reduction on the VALU (DPP), bias + sigmoid
#pragma unroll
    for (int j = 0; j < NH1; ++j)
        h1[j] = sigmoidf_fast(sum16(h1[j]) + b1[j]);

    // ---- layer 2: each lane computes 2 of 32 cols for its row ----
    {
        const float2 bb = *reinterpret_cast<const float2*>(b2 + 2 * ksl);
        float h2a = bb.x, h2b = bb.y;
#pragma unroll
        for (int j = 0; j < NH1; ++j) {
            const float2 w = *reinterpret_cast<const float2*>(&w2l[j * NH2 + 2 * ksl]);
            h2a = fmaf(h1[j], w.x, h2a);
            h2b = fmaf(h1[j], w.y, h2b);
        }
        h2a = sigmoidf_fast(h2a);
        h2b = sigmoidf_fast(h2b);
        *reinterpret_cast<float2*>(&h2l[row][2 * ksl]) = make_float2(h2a, h2b);
    }
    // NO barrier: layer 3 reads only h2l[row][*], written by this lane's own
    // 16-lane group (same wave, lockstep; compiler orders via lgkmcnt).

    // ---- layer 3: lane computes col ksl (and 16+ksl for ksl<2) ----
    {
        float a0 = b3[ksl];
        float a1 = (ksl < 2) ? b3[16 + ksl] : 0.0f;
#pragma unroll
        for (int j = 0; j < NH2; ++j) {
            const float h = h2l[row][j];              // broadcast within 16-group
            a0 = fmaf(h, w3l[j * NH3 + ksl], a0);
            if (ksl < 2) a1 = fmaf(h, w3l[j * NH3 + 16 + ksl], a1);
        }
        wul[row][ksl] = a0;
        out[(size_t)grow * NH3 + ksl] = a0;
        if (ksl < 2) {
            wul[row][16 + ksl] = a1;
            out[(size_t)grow * NH3 + 16 + ksl] = a1;
        }
    }
    __syncthreads();   // epilogue wave reads all 16 rows (cross-wave)

    // ---- epilogue on wave 0: factorized LSE + block reductions ----
    if (t < 64) {
        const bool act = t < RPB;
        float wv[NH3], yv[NH3];
        float ld = 0.0f;
        if (act) {
            const float* yrow = y + (size_t)(blockIdx.x * RPB + t) * NH3;
#pragma unroll
            for (int c = 0; c < NH3; ++c) {
                wv[c] = wul[t][c];
                yv[c] = yrow[c];
            }
            // factorized logsumexp over cartesian one-hot cases:
            // groups [0,2) [2,6) [6,10) [10,18)
            float m = fmaxf(wv[0], wv[1]);
            ld += m + __logf(__expf(wv[0] - m) + __expf(wv[1] - m));
            m = fmaxf(fmaxf(wv[2], wv[3]), fmaxf(wv[4], wv[5]));
            ld += m + __logf(__expf(wv[2] - m) + __expf(wv[3] - m) +
                             __expf(wv[4] - m) + __expf(wv[5] - m));
            m = fmaxf(fmaxf(wv[6], wv[7]), fmaxf(wv[8], wv[9]));
            ld += m + __logf(__expf(wv[6] - m) + __expf(wv[7] - m) +
                             __expf(wv[8] - m) + __expf(wv[9] - m));
            m = wv[10];
#pragma unroll
            for (int i = 11; i < NH3; ++i) m = fmaxf(m, wv[i]);
            float s = 0.0f;
#pragma unroll
            for (int i = 10; i < NH3; ++i) s += __expf(wv[i] - m);
            ld += m + __logf(s);
        } else {
#pragma unroll
            for (int c = 0; c < NH3; ++c) { wv[c] = 0.0f; yv[c] = 0.0f; }
        }

        // 16-lane DPP reductions; lanes 0..15 hold block totals
        ld = sum16(ld);
#pragma unroll
        for (int c = 0; c < NH3; ++c) {
            wv[c] = sum16(wv[c]);
            yv[c] = sum16(yv[c]);
        }
        if (t == 0) {
            float* slot = ws + (size_t)blockIdx.x * WSS;
#pragma unroll
            for (int c = 0; c < NH3; ++c) {
                slot[c]       = yv[c];       // ysum partial
                slot[NH3 + c] = wv[c];       // colsum(W_user) partial
            }
            slot[36] = ld;                   // log_denom partial
        }
    }
}

__global__ __launch_bounds__(256) void finalize_loss(
    const float* __restrict__ ws, float* __restrict__ out)
{
    __shared__ double part[4][37];
    const int t = threadIdx.x;
    const int w = t >> 6, l = t & 63;
    if (l < 37) {
        // 4 independent accumulators: breaks the serial add chain so the
        // 128 global loads pipeline instead of serializing on latency.
        double a0 = 0.0, a1 = 0.0, a2 = 0.0, a3 = 0.0;
        const int base = w * (NBLK / 4);
        for (int b = 0; b < NBLK / 4; b += 4) {
            a0 += (double)ws[(size_t)(base + b    ) * WSS + l];
            a1 += (double)ws[(size_t)(base + b + 1) * WSS + l];
            a2 += (double)ws[(size_t)(base + b + 2) * WSS + l];
            a3 += (double)ws[(size_t)(base + b + 3) * WSS + l];
        }
        part[w][l] = (a0 + a1) + (a2 + a3);
    }
    __syncthreads();
    if (t == 0) {
        double tot[37];
#pragma unroll
        for (int c = 0; c < 37; ++c)
            tot[c] = part[0][c] + part[1][c] + part[2][c] + part[3][c];
        double s = 0.0;
#pragma unroll
        for (int c = 0; c < NH3; ++c)
            s += tot[NH3 + c] * tot[c];             // colsum(W_user) . ysum == sum(S)
        out[(size_t)NB * NH3] = (float)(-(s - tot[36]));
    }
}

extern "C" void kernel_launch(void* const* d_in, const int* in_sizes, int n_in,
                              void* d_out, int out_size, void* d_ws, size_t ws_size,
                              hipStream_t stream) {
    const float* x  = (const float*)d_in[0];
    const float* y  = (const float*)d_in[1];
    const float* W1 = (const float*)d_in[2];
    const float* b1 = (const float*)d_in[3];
    const float* W2 = (const float*)d_in[4];
    const float* b2 = (const float*)d_in[5];
    const float* W3 = (const float*)d_in[6];
    const float* b3 = (const float*)d_in[7];
    // d_in[8] (cases) folded into the factorized logsumexp.
    float* out = (float*)d_out;
    float* ws  = (float*)d_ws;

    fused_main<<<dim3(NBLK), dim3(TPB), 0, stream>>>(x, y, W1, b1, W2, b2, W3, b3, out, ws);
    finalize_loss<<<dim3(1), dim3(256), 0, stream>>>(ws, out);
}